// Round 4
// baseline (2451.571 us; speedup 1.0000x reference)
//
#include <hip/hip_runtime.h>
#include <math.h>

#define B_ 4
#define S_ 2048
#define E_ 1024
#define H_ 16
#define D_ 64

// ---------------------------------------------------------------------------
// GEMM: out = A[M,K=1024] @ W[N,K]^T + bias
// 128x128 tile, BK=32, 256 threads, 8x8 micro-tile (2 chunks of 4 in M and N).
// As row-major [m][k]; Bs k-major [k][n] so B-reads are 64 consecutive floats
// across lanes (2-way alias = free).
// MODE 0: QKV fused — blockIdx.z selects (W,b,out), writes [B,H,S,D] layout.
// MODE 1: row-major [m][f] single output.
// ---------------------------------------------------------------------------
template <int MODE>
__launch_bounds__(256)
__global__ void gemm_bias_k(const float* __restrict__ A,
                            const float* __restrict__ W0,
                            const float* __restrict__ b0,
                            float* __restrict__ o0,
                            const float* __restrict__ W1,
                            const float* __restrict__ b1,
                            float* __restrict__ o1,
                            const float* __restrict__ W2,
                            const float* __restrict__ b2,
                            float* __restrict__ o2)
{
    const float* W = W0; const float* bias = b0; float* out = o0;
    if (MODE == 0) {
        if (blockIdx.z == 1) { W = W1; bias = b1; out = o1; }
        else if (blockIdx.z == 2) { W = W2; bias = b2; out = o2; }
    }

    __shared__ float As[128][36];   // 18 KB
    __shared__ float Bs[32][132];   // 16.9 KB
    const int tid = threadIdx.x;
    const int tx = tid & 15, ty = tid >> 4;
    const int m0 = blockIdx.y * 128;
    const int f0 = blockIdx.x * 128;

    float acc[2][4][2][4] = {};

    for (int k0 = 0; k0 < E_; k0 += 32) {
        __syncthreads();
#pragma unroll
        for (int i = 0; i < 4; ++i) {
            int f4 = tid + i * 256;            // 1024 float4 slots
            int row = f4 >> 3, c4 = (f4 & 7) * 4;
            *(float4*)&As[row][c4] = *(const float4*)&A[(size_t)(m0 + row) * E_ + k0 + c4];
            float4 w = *(const float4*)&W[(size_t)(f0 + row) * E_ + k0 + c4];
            Bs[c4 + 0][row] = w.x; Bs[c4 + 1][row] = w.y;
            Bs[c4 + 2][row] = w.z; Bs[c4 + 3][row] = w.w;
        }
        __syncthreads();

#pragma unroll
        for (int kk = 0; kk < 32; kk += 4) {
            float a_[2][4][4];
            float b_[4][2][4];
#pragma unroll
            for (int mc = 0; mc < 2; ++mc)
#pragma unroll
                for (int i = 0; i < 4; ++i) {
                    float4 t4 = *(const float4*)&As[mc * 64 + ty * 4 + i][kk];
                    a_[mc][i][0] = t4.x; a_[mc][i][1] = t4.y;
                    a_[mc][i][2] = t4.z; a_[mc][i][3] = t4.w;
                }
#pragma unroll
            for (int t = 0; t < 4; ++t)
#pragma unroll
                for (int nc = 0; nc < 2; ++nc) {
                    float4 t4 = *(const float4*)&Bs[kk + t][nc * 64 + tx * 4];
                    b_[t][nc][0] = t4.x; b_[t][nc][1] = t4.y;
                    b_[t][nc][2] = t4.z; b_[t][nc][3] = t4.w;
                }
#pragma unroll
            for (int mc = 0; mc < 2; ++mc)
#pragma unroll
                for (int i = 0; i < 4; ++i)
#pragma unroll
                    for (int nc = 0; nc < 2; ++nc)
#pragma unroll
                        for (int j = 0; j < 4; ++j) {
                            float sum = acc[mc][i][nc][j];
                            sum += a_[mc][i][0] * b_[0][nc][j];
                            sum += a_[mc][i][1] * b_[1][nc][j];
                            sum += a_[mc][i][2] * b_[2][nc][j];
                            sum += a_[mc][i][3] * b_[3][nc][j];
                            acc[mc][i][nc][j] = sum;
                        }
        }
    }

    float bj[2][4];
#pragma unroll
    for (int nc = 0; nc < 2; ++nc)
#pragma unroll
        for (int j = 0; j < 4; ++j) bj[nc][j] = bias[f0 + nc * 64 + tx * 4 + j];

#pragma unroll
    for (int mc = 0; mc < 2; ++mc)
#pragma unroll
        for (int i = 0; i < 4; ++i) {
            const int m = m0 + mc * 64 + ty * 4 + i;
#pragma unroll
            for (int nc = 0; nc < 2; ++nc) {
                float4 o;
                o.x = acc[mc][i][nc][0] + bj[nc][0];
                o.y = acc[mc][i][nc][1] + bj[nc][1];
                o.z = acc[mc][i][nc][2] + bj[nc][2];
                o.w = acc[mc][i][nc][3] + bj[nc][3];
                if (MODE == 0) {
                    const int bb = m >> 11, ss = m & (S_ - 1);
                    const int h = (f0 >> 6) + nc;
                    *(float4*)&out[((size_t)(bb * H_ + h) * S_ + ss) * D_ + tx * 4] = o;
                } else {
                    *(float4*)&out[(size_t)m * E_ + f0 + nc * 64 + tx * 4] = o;
                }
            }
        }
}

// ---------------------------------------------------------------------------
// Flash attention fwd (fp32): per (b,h, 64-row tile). K staged TRANSPOSED in
// LDS ([d][t]) so score B-reads are conflict-free; kst buffer doubles as ps.
// Produces ctx ([B,S,E] layout) and per-row m,l stats.
// ---------------------------------------------------------------------------
__launch_bounds__(256)
__global__ void flash_k(const float* __restrict__ q, const float* __restrict__ k,
                        const float* __restrict__ v, float* __restrict__ ctx,
                        float* __restrict__ mbuf, float* __restrict__ lbuf)
{
    __shared__ float qs[64][68];    // [s][d]
    __shared__ float kst[64][68];   // [d][t]; reused as ps [s][t]
    __shared__ float vs[64][68];    // [t][d]

    const int tid = threadIdx.x;
    const int tx = tid & 15, ty = tid >> 4;
    const int s0 = blockIdx.x * 64;
    const int bh = blockIdx.y;            // b*16+h
    const float scale = 0.125f;           // 1/sqrt(64)

    const float* qb = q + (size_t)bh * S_ * D_;
    const float* kb = k + (size_t)bh * S_ * D_;
    const float* vb = v + (size_t)bh * S_ * D_;

#pragma unroll
    for (int i = 0; i < 4; ++i) {
        int f4 = tid + i * 256;           // 1024 slots
        int row = f4 >> 4, c4 = (f4 & 15) * 4;
        float4 t = *(const float4*)&qb[(size_t)(s0 + row) * D_ + c4];
        t.x *= scale; t.y *= scale; t.z *= scale; t.w *= scale;
        *(float4*)&qs[row][c4] = t;
    }

    float m_run[4], l_run[4], acc[4][4] = {};
#pragma unroll
    for (int i = 0; i < 4; ++i) { m_run[i] = -INFINITY; l_run[i] = 0.f; }

    for (int t0 = 0; t0 < S_; t0 += 64) {
        __syncthreads();                  // prev iter done reading kst(ps)/vs
#pragma unroll
        for (int i = 0; i < 4; ++i) {
            int f4 = tid + i * 256;
            int row = f4 >> 4, c4 = (f4 & 15) * 4;   // row = t index, c4 = d
            float4 kt = *(const float4*)&kb[(size_t)(t0 + row) * D_ + c4];
            kst[c4 + 0][row] = kt.x; kst[c4 + 1][row] = kt.y;
            kst[c4 + 2][row] = kt.z; kst[c4 + 3][row] = kt.w;
            *(float4*)&vs[row][c4] = *(const float4*)&vb[(size_t)(t0 + row) * D_ + c4];
        }
        __syncthreads();

        // scores: rows = ty*4+i, cols = tx*4+j; kst[d][t]
        float s[4][4] = {};
#pragma unroll
        for (int kk = 0; kk < 64; kk += 4) {
            float a_[4][4], b_[4][4];
#pragma unroll
            for (int i = 0; i < 4; ++i) {
                float4 t4 = *(const float4*)&qs[ty * 4 + i][kk];
                a_[i][0] = t4.x; a_[i][1] = t4.y; a_[i][2] = t4.z; a_[i][3] = t4.w;
            }
#pragma unroll
            for (int dd = 0; dd < 4; ++dd) {
                float4 t4 = *(const float4*)&kst[kk + dd][tx * 4];
                b_[dd][0] = t4.x; b_[dd][1] = t4.y; b_[dd][2] = t4.z; b_[dd][3] = t4.w;
            }
#pragma unroll
            for (int i = 0; i < 4; ++i)
#pragma unroll
                for (int j = 0; j < 4; ++j) {
                    float sum = s[i][j];
                    sum += a_[i][0] * b_[0][j];
                    sum += a_[i][1] * b_[1][j];
                    sum += a_[i][2] * b_[2][j];
                    sum += a_[i][3] * b_[3][j];
                    s[i][j] = sum;
                }
        }

        // online softmax update (row spans the 16 tx lanes: shfl width 16)
        float p[4][4];
#pragma unroll
        for (int i = 0; i < 4; ++i) {
            float mt = fmaxf(fmaxf(s[i][0], s[i][1]), fmaxf(s[i][2], s[i][3]));
#pragma unroll
            for (int off = 1; off < 16; off <<= 1)
                mt = fmaxf(mt, __shfl_xor(mt, off, 16));
            float mn = fmaxf(m_run[i], mt);
            float alpha = __expf(m_run[i] - mn);
            float sig = 0.f;
#pragma unroll
            for (int j = 0; j < 4; ++j) { p[i][j] = __expf(s[i][j] - mn); sig += p[i][j]; }
#pragma unroll
            for (int off = 1; off < 16; off <<= 1)
                sig += __shfl_xor(sig, off, 16);
            l_run[i] = l_run[i] * alpha + sig;
            m_run[i] = mn;
#pragma unroll
            for (int j = 0; j < 4; ++j) acc[i][j] *= alpha;
        }

        __syncthreads();                  // QK^T reads of kst done
#pragma unroll
        for (int i = 0; i < 4; ++i) {
            float4 o; o.x = p[i][0]; o.y = p[i][1]; o.z = p[i][2]; o.w = p[i][3];
            *(float4*)&kst[ty * 4 + i][tx * 4] = o;   // ps[s][t]
        }
        __syncthreads();

        // ctx += ps[64x64] @ vs[64x64]; d-cols = tx*4+j
#pragma unroll
        for (int c4 = 0; c4 < 64; c4 += 4) {
            float ap[4][4], vv[4][4];
#pragma unroll
            for (int i = 0; i < 4; ++i) {
                float4 t4 = *(const float4*)&kst[ty * 4 + i][c4];
                ap[i][0] = t4.x; ap[i][1] = t4.y; ap[i][2] = t4.z; ap[i][3] = t4.w;
            }
#pragma unroll
            for (int cc = 0; cc < 4; ++cc) {
                float4 t4 = *(const float4*)&vs[c4 + cc][tx * 4];
                vv[cc][0] = t4.x; vv[cc][1] = t4.y; vv[cc][2] = t4.z; vv[cc][3] = t4.w;
            }
#pragma unroll
            for (int i = 0; i < 4; ++i)
#pragma unroll
                for (int j = 0; j < 4; ++j) {
                    float sum = acc[i][j];
                    sum += ap[i][0] * vv[0][j];
                    sum += ap[i][1] * vv[1][j];
                    sum += ap[i][2] * vv[2][j];
                    sum += ap[i][3] * vv[3][j];
                    acc[i][j] = sum;
                }
        }
    }

    const int b = bh >> 4, h = bh & 15;
#pragma unroll
    for (int i = 0; i < 4; ++i) {
        const float linv = 1.f / l_run[i];
        const int srow = s0 + ty * 4 + i;
        float4 o;
        o.x = acc[i][0] * linv; o.y = acc[i][1] * linv;
        o.z = acc[i][2] * linv; o.w = acc[i][3] * linv;
        *(float4*)&ctx[((size_t)(b * S_ + srow)) * E_ + h * D_ + tx * 4] = o;
    }
    if (tx == 0) {
#pragma unroll
        for (int i = 0; i < 4; ++i) {
            mbuf[(size_t)bh * S_ + s0 + ty * 4 + i] = m_run[i];
            lbuf[(size_t)bh * S_ + s0 + ty * 4 + i] = l_run[i];
        }
    }
}

// ---------------------------------------------------------------------------
// attn_avg: per (b, 64 s-rows, 64 t-cols), recompute scores for all 16 heads
// using saved m,l; accumulate mean. K staged transposed (conflict-free reads).
// ---------------------------------------------------------------------------
__launch_bounds__(256)
__global__ void avg_k(const float* __restrict__ q, const float* __restrict__ k,
                      const float* __restrict__ mbuf, const float* __restrict__ lbuf,
                      float* __restrict__ avg_out)
{
    __shared__ float qs[64][68];    // [s][d]
    __shared__ float kst[64][68];   // [d][t]

    const int tid = threadIdx.x;
    const int tx = tid & 15, ty = tid >> 4;
    const int b = blockIdx.z;
    const int s0 = blockIdx.y * 64;
    const int t0 = blockIdx.x * 64;
    const float scale = 0.125f;

    float acc[4][4] = {};

    for (int h = 0; h < H_; ++h) {
        const int bh = b * H_ + h;
        const float* qb = q + (size_t)bh * S_ * D_;
        const float* kb = k + (size_t)bh * S_ * D_;
        __syncthreads();
#pragma unroll
        for (int i = 0; i < 4; ++i) {
            int f4 = tid + i * 256;
            int row = f4 >> 4, c4 = (f4 & 15) * 4;
            float4 t = *(const float4*)&qb[(size_t)(s0 + row) * D_ + c4];
            t.x *= scale; t.y *= scale; t.z *= scale; t.w *= scale;
            *(float4*)&qs[row][c4] = t;
            float4 kt = *(const float4*)&kb[(size_t)(t0 + row) * D_ + c4];
            kst[c4 + 0][row] = kt.x; kst[c4 + 1][row] = kt.y;
            kst[c4 + 2][row] = kt.z; kst[c4 + 3][row] = kt.w;
        }
        __syncthreads();

        float mv[4], li[4];
#pragma unroll
        for (int i = 0; i < 4; ++i) {
            mv[i] = mbuf[(size_t)bh * S_ + s0 + ty * 4 + i];
            li[i] = 1.f / lbuf[(size_t)bh * S_ + s0 + ty * 4 + i];
        }

        float s[4][4] = {};
#pragma unroll
        for (int kk = 0; kk < 64; kk += 4) {
            float a_[4][4], b_[4][4];
#pragma unroll
            for (int i = 0; i < 4; ++i) {
                float4 t4 = *(const float4*)&qs[ty * 4 + i][kk];
                a_[i][0] = t4.x; a_[i][1] = t4.y; a_[i][2] = t4.z; a_[i][3] = t4.w;
            }
#pragma unroll
            for (int dd = 0; dd < 4; ++dd) {
                float4 t4 = *(const float4*)&kst[kk + dd][tx * 4];
                b_[dd][0] = t4.x; b_[dd][1] = t4.y; b_[dd][2] = t4.z; b_[dd][3] = t4.w;
            }
#pragma unroll
            for (int i = 0; i < 4; ++i)
#pragma unroll
                for (int j = 0; j < 4; ++j) {
                    float sum = s[i][j];
                    sum += a_[i][0] * b_[0][j];
                    sum += a_[i][1] * b_[1][j];
                    sum += a_[i][2] * b_[2][j];
                    sum += a_[i][3] * b_[3][j];
                    s[i][j] = sum;
                }
        }
#pragma unroll
        for (int i = 0; i < 4; ++i)
#pragma unroll
            for (int j = 0; j < 4; ++j)
                acc[i][j] += __expf(s[i][j] - mv[i]) * li[i];
    }

    const float invH = 1.f / (float)H_;
#pragma unroll
    for (int i = 0; i < 4; ++i) {
        const int srow = s0 + ty * 4 + i;
        float4 o;
        o.x = acc[i][0] * invH; o.y = acc[i][1] * invH;
        o.z = acc[i][2] * invH; o.w = acc[i][3] * invH;
        *(float4*)&avg_out[((size_t)(b * S_ + srow)) * S_ + t0 + tx * 4] = o;
    }
}

// ---------------------------------------------------------------------------
extern "C" void kernel_launch(void* const* d_in, const int* in_sizes, int n_in,
                              void* d_out, int out_size, void* d_ws, size_t ws_size,
                              hipStream_t stream)
{
    const float* x  = (const float*)d_in[0];
    const float* Wq = (const float*)d_in[1];
    const float* bq = (const float*)d_in[2];
    const float* Wk = (const float*)d_in[3];
    const float* bk = (const float*)d_in[4];
    const float* Wv = (const float*)d_in[5];
    const float* bv = (const float*)d_in[6];
    const float* Wo = (const float*)d_in[7];
    const float* bo = (const float*)d_in[8];

    float* out = (float*)d_out;                       // [B,S,E] then [B,S,S]
    float* avg = out + (size_t)B_ * S_ * E_;          // [B,S,S] = 16M floats

    // ctx staged inside the avg output region (8M floats of 16M available);
    // consumed by the out-projection BEFORE avg_k overwrites the region.
    float* ctxw = avg;

    float* ws = (float*)d_ws;                         // ~97 MB
    float* qw = ws;                                   // [B,H,S,D]
    float* kw = qw + (size_t)B_ * H_ * S_ * D_;
    float* vw = kw + (size_t)B_ * H_ * S_ * D_;
    float* mb = vw + (size_t)B_ * H_ * S_ * D_;       // [B,H,S]
    float* lb = mb + (size_t)B_ * H_ * S_;

    const dim3 blk(256);

    // fused QKV projections: z selects (W, b, out)
    gemm_bias_k<0><<<dim3(E_ / 128, (B_ * S_) / 128, 3), blk, 0, stream>>>(
        x, Wq, bq, qw, Wk, bk, kw, Wv, bv, vw);

    flash_k<<<dim3(S_ / 64, B_ * H_), blk, 0, stream>>>(qw, kw, vw, ctxw, mb, lb);

    gemm_bias_k<1><<<dim3(E_ / 128, (B_ * S_) / 128, 1), blk, 0, stream>>>(
        ctxw, Wo, bo, out, nullptr, nullptr, nullptr, nullptr, nullptr, nullptr);

    avg_k<<<dim3(S_ / 64, S_ / 64, B_), blk, 0, stream>>>(qw, kw, mb, lb, avg);
}

// Round 5
// 631.610 us; speedup vs baseline: 3.8815x; 3.8815x over previous
//
#include <hip/hip_runtime.h>
#include <math.h>

#define B_ 4
#define S_ 2048
#define E_ 1024
#define H_ 16
#define D_ 64

typedef __attribute__((ext_vector_type(8))) short bf16x8;
typedef __attribute__((ext_vector_type(4))) short bf16x4;
typedef __attribute__((ext_vector_type(4))) float f32x4;

#define MFMA(a, b, c) __builtin_amdgcn_mfma_f32_16x16x32_bf16((a), (b), (c), 0, 0, 0)

static __device__ __forceinline__ short f2bf(float f) {
    unsigned u = __float_as_uint(f);
    unsigned r = (u + 0x7FFFu + ((u >> 16) & 1u)) >> 16;   // RNE
    return (short)r;
}

// ---------------------------------------------------------------------------
// GEMM (bf16 MFMA): y = A[M,1024] @ W[N,1024]^T + bias
// 128x128 tile, BK=64, 4 waves in 2x2, each wave 4x4 MFMA tiles (16x16x32).
// MODE 0: A fp32 (x). blockIdx.z = {q,k,v}: q scaled by 0.125, q/k -> bf16
//         [B,H,S,D]; v -> bf16 transposed [B,H,D,S].
// MODE 1: A bf16 (ctx). fp32 output [m][f] + bias.
// LDS rows padded to 72 bf16 (144B): frag reads are 2-way bank alias (free).
// ---------------------------------------------------------------------------
template <int MODE>
__launch_bounds__(256)
__global__ void gemm_mfma(const float* __restrict__ Af,
                          const short* __restrict__ Ab,
                          const float* __restrict__ W0, const float* __restrict__ b0,
                          short* __restrict__ o0,
                          const float* __restrict__ W1, const float* __restrict__ b1,
                          short* __restrict__ o1,
                          const float* __restrict__ W2, const float* __restrict__ b2,
                          short* __restrict__ o2,
                          float* __restrict__ of)
{
    const float* W = W0; const float* bias = b0; short* ob = o0;
    const int z = blockIdx.z;
    if (MODE == 0) {
        if (z == 1) { W = W1; bias = b1; ob = o1; }
        else if (z == 2) { W = W2; bias = b2; ob = o2; }
    }

    __shared__ short a_lds[128][72];
    __shared__ short b_lds[128][72];

    const int tid = threadIdx.x;
    const int l = tid & 63, w = tid >> 6;
    const int wm = w >> 1, wn = w & 1;
    const int lr = l & 15, lg = l >> 4;
    const int m0 = blockIdx.y * 128, f0 = blockIdx.x * 128;

    f32x4 acc[4][4];
#pragma unroll
    for (int i = 0; i < 4; ++i)
#pragma unroll
        for (int j = 0; j < 4; ++j) { acc[i][j][0] = 0.f; acc[i][j][1] = 0.f; acc[i][j][2] = 0.f; acc[i][j][3] = 0.f; }

    for (int k0 = 0; k0 < E_; k0 += 64) {
        __syncthreads();
        if (MODE == 0) {
#pragma unroll
            for (int i = 0; i < 8; ++i) {
                int idx = tid + i * 256;            // 2048 float4 slots
                int row = idx >> 4, c4 = (idx & 15) * 4;
                float4 t = *(const float4*)&Af[(size_t)(m0 + row) * E_ + k0 + c4];
                bf16x4 v; v[0] = f2bf(t.x); v[1] = f2bf(t.y); v[2] = f2bf(t.z); v[3] = f2bf(t.w);
                *(bf16x4*)&a_lds[row][c4] = v;
            }
        } else {
#pragma unroll
            for (int i = 0; i < 4; ++i) {
                int idx = tid + i * 256;            // 1024 8-bf16 slots
                int row = idx >> 3, c8 = (idx & 7) * 8;
                *(bf16x8*)&a_lds[row][c8] = *(const bf16x8*)&Ab[(size_t)(m0 + row) * E_ + k0 + c8];
            }
        }
#pragma unroll
        for (int i = 0; i < 8; ++i) {
            int idx = tid + i * 256;
            int row = idx >> 4, c4 = (idx & 15) * 4;
            float4 t = *(const float4*)&W[(size_t)(f0 + row) * E_ + k0 + c4];
            bf16x4 v; v[0] = f2bf(t.x); v[1] = f2bf(t.y); v[2] = f2bf(t.z); v[3] = f2bf(t.w);
            *(bf16x4*)&b_lds[row][c4] = v;
        }
        __syncthreads();

        bf16x8 a[4][2];
#pragma unroll
        for (int mt = 0; mt < 4; ++mt)
#pragma unroll
            for (int c = 0; c < 2; ++c)
                a[mt][c] = *(const bf16x8*)&a_lds[wm * 64 + mt * 16 + lr][c * 32 + lg * 8];
#pragma unroll
        for (int nt = 0; nt < 4; ++nt) {
            bf16x8 bq0 = *(const bf16x8*)&b_lds[wn * 64 + nt * 16 + lr][lg * 8];
            bf16x8 bq1 = *(const bf16x8*)&b_lds[wn * 64 + nt * 16 + lr][32 + lg * 8];
#pragma unroll
            for (int mt = 0; mt < 4; ++mt) {
                acc[mt][nt] = MFMA(a[mt][0], bq0, acc[mt][nt]);
                acc[mt][nt] = MFMA(a[mt][1], bq1, acc[mt][nt]);
            }
        }
    }

    float bv[4];
#pragma unroll
    for (int nt = 0; nt < 4; ++nt) bv[nt] = bias[f0 + wn * 64 + nt * 16 + lr];

#pragma unroll
    for (int mt = 0; mt < 4; ++mt)
#pragma unroll
        for (int nt = 0; nt < 4; ++nt)
#pragma unroll
            for (int r = 0; r < 4; ++r) {
                const int m = m0 + wm * 64 + mt * 16 + lg * 4 + r;
                const int f = f0 + wn * 64 + nt * 16 + lr;
                float val = acc[mt][nt][r] + bv[nt];
                if (MODE == 0) {
                    const int bb = m >> 11, ss = m & (S_ - 1);
                    const int h = f >> 6, d = f & 63;
                    if (z == 0)
                        ob[((size_t)(bb * H_ + h) * S_ + ss) * D_ + d] = f2bf(val * 0.125f);
                    else if (z == 1)
                        ob[((size_t)(bb * H_ + h) * S_ + ss) * D_ + d] = f2bf(val);
                    else
                        ob[((size_t)(bb * H_ + h) * D_ + d) * S_ + ss] = f2bf(val);
                } else {
                    of[(size_t)m * E_ + f] = val;
                }
            }
}

// ---------------------------------------------------------------------------
// Flash attention fwd, bf16 MFMA: per (b,h, 64-row q-tile). 4 waves, each owns
// 16 q-rows. K tile [t][d], V^T tile [d][t], P in wave-private LDS rows.
// q pre-scaled at projection. Outputs ctx bf16 [B,S,E] + fp32 m,l.
// ---------------------------------------------------------------------------
__launch_bounds__(256)
__global__ void flash_mfma(const short* __restrict__ q, const short* __restrict__ k,
                           const short* __restrict__ vt, short* __restrict__ ctx,
                           float* __restrict__ mbuf, float* __restrict__ lbuf)
{
    __shared__ short k_lds[64][72];
    __shared__ short vt_lds[64][72];
    __shared__ short p_lds[64][72];

    const int tid = threadIdx.x;
    const int l = tid & 63, w = tid >> 6;
    const int lr = l & 15, lg = l >> 4;
    const int s0 = blockIdx.x * 64;
    const int bh = blockIdx.y;

    const short* qb  = q  + (size_t)bh * S_ * D_;
    const short* kb  = k  + (size_t)bh * S_ * D_;
    const short* vtb = vt + (size_t)bh * D_ * S_;

    bf16x8 qa[2];
#pragma unroll
    for (int c = 0; c < 2; ++c)
        qa[c] = *(const bf16x8*)&qb[(size_t)(s0 + w * 16 + lr) * D_ + c * 32 + lg * 8];

    float m_run[4], l_run[4];
    f32x4 cacc[4];
#pragma unroll
    for (int r = 0; r < 4; ++r) { m_run[r] = -1e30f; l_run[r] = 0.f; }
#pragma unroll
    for (int dt = 0; dt < 4; ++dt) { cacc[dt][0] = 0.f; cacc[dt][1] = 0.f; cacc[dt][2] = 0.f; cacc[dt][3] = 0.f; }

    for (int t0 = 0; t0 < S_; t0 += 64) {
        __syncthreads();
#pragma unroll
        for (int i = 0; i < 2; ++i) {
            int idx = tid + i * 256;            // 512 8-bf16 slots
            int row = idx >> 3, c8 = (idx & 7) * 8;
            *(bf16x8*)&k_lds[row][c8]  = *(const bf16x8*)&kb[(size_t)(t0 + row) * D_ + c8];
            *(bf16x8*)&vt_lds[row][c8] = *(const bf16x8*)&vtb[(size_t)row * S_ + t0 + c8];
        }
        __syncthreads();

        f32x4 sc[4];
#pragma unroll
        for (int nt = 0; nt < 4; ++nt) {
            sc[nt][0] = 0.f; sc[nt][1] = 0.f; sc[nt][2] = 0.f; sc[nt][3] = 0.f;
            bf16x8 k0f = *(const bf16x8*)&k_lds[nt * 16 + lr][lg * 8];
            bf16x8 k1f = *(const bf16x8*)&k_lds[nt * 16 + lr][32 + lg * 8];
            sc[nt] = MFMA(qa[0], k0f, sc[nt]);
            sc[nt] = MFMA(qa[1], k1f, sc[nt]);
        }

        // online softmax: row = lg*4+r, cols span {nt, lr}
#pragma unroll
        for (int r = 0; r < 4; ++r) {
            float mt_ = fmaxf(fmaxf(sc[0][r], sc[1][r]), fmaxf(sc[2][r], sc[3][r]));
#pragma unroll
            for (int off = 1; off < 16; off <<= 1)
                mt_ = fmaxf(mt_, __shfl_xor(mt_, off, 16));
            const float mn = fmaxf(m_run[r], mt_);
            const float al = __expf(m_run[r] - mn);
            float sig = 0.f;
#pragma unroll
            for (int nt = 0; nt < 4; ++nt) {
                float p = __expf(sc[nt][r] - mn);
                sig += p;
                p_lds[w * 16 + lg * 4 + r][nt * 16 + lr] = f2bf(p);
            }
#pragma unroll
            for (int off = 1; off < 16; off <<= 1)
                sig += __shfl_xor(sig, off, 16);
            m_run[r] = mn;
            l_run[r] = l_run[r] * al + sig;
#pragma unroll
            for (int dt = 0; dt < 4; ++dt) cacc[dt][r] *= al;
        }

        // PV: ctx += P @ V   (P wave-private rows; no barrier needed)
        bf16x8 pa[2];
#pragma unroll
        for (int c = 0; c < 2; ++c)
            pa[c] = *(const bf16x8*)&p_lds[w * 16 + lr][c * 32 + lg * 8];
#pragma unroll
        for (int dt = 0; dt < 4; ++dt) {
            bf16x8 v0f = *(const bf16x8*)&vt_lds[dt * 16 + lr][lg * 8];
            bf16x8 v1f = *(const bf16x8*)&vt_lds[dt * 16 + lr][32 + lg * 8];
            cacc[dt] = MFMA(pa[0], v0f, cacc[dt]);
            cacc[dt] = MFMA(pa[1], v1f, cacc[dt]);
        }
    }

    const int b = bh >> 4, h = bh & 15;
#pragma unroll
    for (int r = 0; r < 4; ++r) {
        const float linv = 1.f / l_run[r];
        const int srow = s0 + w * 16 + lg * 4 + r;
#pragma unroll
        for (int dt = 0; dt < 4; ++dt)
            ctx[((size_t)(b * S_ + srow)) * E_ + h * D_ + dt * 16 + lr] = f2bf(cacc[dt][r] * linv);
        if (lr == 0) {
            mbuf[(size_t)bh * S_ + srow] = m_run[r];
            lbuf[(size_t)bh * S_ + srow] = l_run[r];
        }
    }
}

// ---------------------------------------------------------------------------
// attn_avg, bf16 MFMA: per (b, 128 s-rows, 128 t-cols), loop 16 heads,
// recompute scores (bitwise-identical MFMA to flash) with saved m,l.
// ---------------------------------------------------------------------------
__launch_bounds__(256)
__global__ void avg_mfma(const short* __restrict__ q, const short* __restrict__ k,
                         const float* __restrict__ mbuf, const float* __restrict__ lbuf,
                         float* __restrict__ avg)
{
    __shared__ short qs[128][72];
    __shared__ short ks[128][72];

    const int tid = threadIdx.x;
    const int l = tid & 63, w = tid >> 6;
    const int lr = l & 15, lg = l >> 4;
    const int b = blockIdx.z;
    const int s0 = blockIdx.y * 128;
    const int t0 = blockIdx.x * 128;

    f32x4 acc[2][8];
#pragma unroll
    for (int mt = 0; mt < 2; ++mt)
#pragma unroll
        for (int nt = 0; nt < 8; ++nt) { acc[mt][nt][0] = 0.f; acc[mt][nt][1] = 0.f; acc[mt][nt][2] = 0.f; acc[mt][nt][3] = 0.f; }

    for (int h = 0; h < H_; ++h) {
        const int bh = b * H_ + h;
        const short* qb = q + (size_t)bh * S_ * D_;
        const short* kb = k + (size_t)bh * S_ * D_;
        __syncthreads();
#pragma unroll
        for (int i = 0; i < 4; ++i) {
            int idx = tid + i * 256;            // 1024 8-bf16 slots
            int row = idx >> 3, c8 = (idx & 7) * 8;
            *(bf16x8*)&qs[row][c8] = *(const bf16x8*)&qb[(size_t)(s0 + row) * D_ + c8];
            *(bf16x8*)&ks[row][c8] = *(const bf16x8*)&kb[(size_t)(t0 + row) * D_ + c8];
        }
        __syncthreads();

#pragma unroll
        for (int mt = 0; mt < 2; ++mt) {
            bf16x8 qa0 = *(const bf16x8*)&qs[w * 32 + mt * 16 + lr][lg * 8];
            bf16x8 qa1 = *(const bf16x8*)&qs[w * 32 + mt * 16 + lr][32 + lg * 8];
            float mv[4], li[4];
#pragma unroll
            for (int r = 0; r < 4; ++r) {
                const int srow = s0 + w * 32 + mt * 16 + lg * 4 + r;
                mv[r] = mbuf[(size_t)bh * S_ + srow];
                li[r] = 1.f / lbuf[(size_t)bh * S_ + srow];
            }
#pragma unroll
            for (int nt = 0; nt < 8; ++nt) {
                bf16x8 kb0 = *(const bf16x8*)&ks[nt * 16 + lr][lg * 8];
                bf16x8 kb1 = *(const bf16x8*)&ks[nt * 16 + lr][32 + lg * 8];
                f32x4 sv; sv[0] = 0.f; sv[1] = 0.f; sv[2] = 0.f; sv[3] = 0.f;
                sv = MFMA(qa0, kb0, sv);
                sv = MFMA(qa1, kb1, sv);
#pragma unroll
                for (int r = 0; r < 4; ++r)
                    acc[mt][nt][r] += __expf(sv[r] - mv[r]) * li[r];
            }
        }
    }

#pragma unroll
    for (int mt = 0; mt < 2; ++mt)
#pragma unroll
        for (int nt = 0; nt < 8; ++nt)
#pragma unroll
            for (int r = 0; r < 4; ++r) {
                const int srow = s0 + w * 32 + mt * 16 + lg * 4 + r;
                avg[((size_t)(b * S_ + srow)) * S_ + t0 + nt * 16 + lr] = acc[mt][nt][r] * 0.0625f;
            }
}

// ---------------------------------------------------------------------------
extern "C" void kernel_launch(void* const* d_in, const int* in_sizes, int n_in,
                              void* d_out, int out_size, void* d_ws, size_t ws_size,
                              hipStream_t stream)
{
    const float* x  = (const float*)d_in[0];
    const float* Wq = (const float*)d_in[1];
    const float* bq = (const float*)d_in[2];
    const float* Wk = (const float*)d_in[3];
    const float* bk = (const float*)d_in[4];
    const float* Wv = (const float*)d_in[5];
    const float* bv = (const float*)d_in[6];
    const float* Wo = (const float*)d_in[7];
    const float* bo = (const float*)d_in[8];

    float* out = (float*)d_out;                        // [B,S,E] fp32
    float* avg = out + (size_t)B_ * S_ * E_;           // [B,S,S] fp32

    short* qw   = (short*)d_ws;                        // bf16 [B,H,S,D] (q pre-scaled)
    short* kw   = qw + (size_t)B_ * H_ * S_ * D_;      // bf16 [B,H,S,D]
    short* vtw  = kw + (size_t)B_ * H_ * S_ * D_;      // bf16 [B,H,D,S]
    short* ctxw = vtw + (size_t)B_ * H_ * S_ * D_;     // bf16 [B,S,E]
    float* mb   = (float*)(ctxw + (size_t)B_ * S_ * E_);
    float* lb   = mb + (size_t)B_ * H_ * S_;           // total ~68 MB of d_ws

    // QKV projections (z = 0:q, 1:k, 2:v-transposed)
    gemm_mfma<0><<<dim3(E_ / 128, (B_ * S_) / 128, 3), 256, 0, stream>>>(
        x, nullptr, Wq, bq, qw, Wk, bk, kw, Wv, bv, vtw, nullptr);

    flash_mfma<<<dim3(S_ / 64, B_ * H_), 256, 0, stream>>>(qw, kw, vtw, ctxw, mb, lb);

    gemm_mfma<1><<<dim3(E_ / 128, (B_ * S_) / 128, 1), 256, 0, stream>>>(
        nullptr, ctxw, Wo, bo, nullptr,
        nullptr, nullptr, nullptr, nullptr, nullptr, nullptr, out);

    avg_mfma<<<dim3(S_ / 128, S_ / 128, B_), 256, 0, stream>>>(qw, kw, mb, lb, avg);
}

// Round 7
// 602.429 us; speedup vs baseline: 4.0695x; 1.0484x over previous
//
#include <hip/hip_runtime.h>
#include <hip/hip_bf16.h>
#include <math.h>

#define B_ 4
#define S_ 2048
#define E_ 1024
#define H_ 16
#define D_ 64

typedef __attribute__((ext_vector_type(8))) short bf16x8;
typedef __attribute__((ext_vector_type(4))) float f32x4;

#define MFMA(a, b, c) __builtin_amdgcn_mfma_f32_16x16x32_bf16((a), (b), (c), 0, 0, 0)

#if __has_builtin(__builtin_amdgcn_exp2f)
#define EXP2(x) __builtin_amdgcn_exp2f(x)
#else
#define EXP2(x) __expf(0.69314718f * (x))
#endif

#if __has_builtin(__builtin_amdgcn_rcpf)
#define RCP(x) __builtin_amdgcn_rcpf(x)
#else
#define RCP(x) (1.0f / (x))
#endif

// q pre-scale: 0.125 (=1/sqrt(64)) * log2(e) so softmax runs in base-2 domain
#define QSCALE 0.18033688011112042f

static __device__ __forceinline__ short f2bf(float f) {
    __hip_bfloat16 h = __float2bfloat16(f);       // RNE; compiler emits v_cvt_pk_bf16_f32
    return *reinterpret_cast<short*>(&h);
}

// ---------------------------------------------------------------------------
// One-time fp32 -> bf16 conversion of x and the four weight matrices.
// grid (512, 5): z = {x, Wq, Wk, Wv, Wo}. 8 elements/thread via float4 pairs.
// ---------------------------------------------------------------------------
__launch_bounds__(256)
__global__ void cvt_bf16_5(const float* __restrict__ x,  const float* __restrict__ wq,
                           const float* __restrict__ wk, const float* __restrict__ wv,
                           const float* __restrict__ wo,
                           short* __restrict__ xb,  short* __restrict__ wqb,
                           short* __restrict__ wkb, short* __restrict__ wvb,
                           short* __restrict__ wob)
{
    const int z = blockIdx.y;
    const float* src; short* dst; int n;
    if (z == 0)      { src = x;  dst = xb;  n = B_ * S_ * E_; }
    else if (z == 1) { src = wq; dst = wqb; n = E_ * E_; }
    else if (z == 2) { src = wk; dst = wkb; n = E_ * E_; }
    else if (z == 3) { src = wv; dst = wvb; n = E_ * E_; }
    else             { src = wo; dst = wob; n = E_ * E_; }

    for (int base = (blockIdx.x * 256 + threadIdx.x) * 8; base < n; base += 512 * 256 * 8) {
        float4 a = *(const float4*)&src[base];
        float4 b = *(const float4*)&src[base + 4];
        bf16x8 v;
        v[0] = f2bf(a.x); v[1] = f2bf(a.y); v[2] = f2bf(a.z); v[3] = f2bf(a.w);
        v[4] = f2bf(b.x); v[5] = f2bf(b.y); v[6] = f2bf(b.z); v[7] = f2bf(b.w);
        *(bf16x8*)&dst[base] = v;
    }
}

// ---------------------------------------------------------------------------
// GEMM (bf16 MFMA): y = A[M,1024] @ W[N,1024]^T + bias.  A, W already bf16.
// 128x128 tile, BK=64, 4 waves 2x2, each wave 4x4 MFMA tiles of 16x16x32.
// MODE 0: blockIdx.z = {q,k,v}: q scaled by QSCALE -> bf16 [B,H,S,D];
//         k -> bf16 [B,H,S,D]; v -> bf16 transposed [B,H,D,S].
// MODE 1: fp32 output [m][f] + bias.
// ---------------------------------------------------------------------------
template <int MODE>
__launch_bounds__(256)
__global__ void gemm_mfma(const short* __restrict__ A,
                          const short* __restrict__ W0, const float* __restrict__ b0,
                          short* __restrict__ o0,
                          const short* __restrict__ W1, const float* __restrict__ b1,
                          short* __restrict__ o1,
                          const short* __restrict__ W2, const float* __restrict__ b2,
                          short* __restrict__ o2,
                          float* __restrict__ of)
{
    const short* W = W0; const float* bias = b0; short* ob = o0;
    const int z = blockIdx.z;
    if (MODE == 0) {
        if (z == 1) { W = W1; bias = b1; ob = o1; }
        else if (z == 2) { W = W2; bias = b2; ob = o2; }
    }

    __shared__ short a_lds[128][72];
    __shared__ short b_lds[128][72];

    const int tid = threadIdx.x;
    const int l = tid & 63, w = tid >> 6;
    const int wm = w >> 1, wn = w & 1;
    const int lr = l & 15, lg = l >> 4;
    const int m0 = blockIdx.y * 128, f0 = blockIdx.x * 128;

    f32x4 acc[4][4];
#pragma unroll
    for (int i = 0; i < 4; ++i)
#pragma unroll
        for (int j = 0; j < 4; ++j) { acc[i][j][0] = 0.f; acc[i][j][1] = 0.f; acc[i][j][2] = 0.f; acc[i][j][3] = 0.f; }

    for (int k0 = 0; k0 < E_; k0 += 64) {
        __syncthreads();
#pragma unroll
        for (int i = 0; i < 4; ++i) {
            int idx = tid + i * 256;            // 1024 8-bf16 slots
            int row = idx >> 3, c8 = (idx & 7) * 8;
            *(bf16x8*)&a_lds[row][c8] = *(const bf16x8*)&A[(size_t)(m0 + row) * E_ + k0 + c8];
            *(bf16x8*)&b_lds[row][c8] = *(const bf16x8*)&W[(size_t)(f0 + row) * E_ + k0 + c8];
        }
        __syncthreads();

        bf16x8 a[4][2];
#pragma unroll
        for (int mt = 0; mt < 4; ++mt)
#pragma unroll
            for (int c = 0; c < 2; ++c)
                a[mt][c] = *(const bf16x8*)&a_lds[wm * 64 + mt * 16 + lr][c * 32 + lg * 8];
#pragma unroll
        for (int nt = 0; nt < 4; ++nt) {
            bf16x8 bq0 = *(const bf16x8*)&b_lds[wn * 64 + nt * 16 + lr][lg * 8];
            bf16x8 bq1 = *(const bf16x8*)&b_lds[wn * 64 + nt * 16 + lr][32 + lg * 8];
#pragma unroll
            for (int mt = 0; mt < 4; ++mt) {
                acc[mt][nt] = MFMA(a[mt][0], bq0, acc[mt][nt]);
                acc[mt][nt] = MFMA(a[mt][1], bq1, acc[mt][nt]);
            }
        }
    }

    float bv[4];
#pragma unroll
    for (int nt = 0; nt < 4; ++nt) bv[nt] = bias[f0 + wn * 64 + nt * 16 + lr];

#pragma unroll
    for (int mt = 0; mt < 4; ++mt)
#pragma unroll
        for (int nt = 0; nt < 4; ++nt)
#pragma unroll
            for (int r = 0; r < 4; ++r) {
                const int m = m0 + wm * 64 + mt * 16 + lg * 4 + r;
                const int f = f0 + wn * 64 + nt * 16 + lr;
                float val = acc[mt][nt][r] + bv[nt];
                if (MODE == 0) {
                    const int bb = m >> 11, ss = m & (S_ - 1);
                    const int h = f >> 6, d = f & 63;
                    if (z == 0)
                        ob[((size_t)(bb * H_ + h) * S_ + ss) * D_ + d] = f2bf(val * QSCALE);
                    else if (z == 1)
                        ob[((size_t)(bb * H_ + h) * S_ + ss) * D_ + d] = f2bf(val);
                    else
                        ob[((size_t)(bb * H_ + h) * D_ + d) * S_ + ss] = f2bf(val);
                } else {
                    of[(size_t)m * E_ + f] = val;
                }
            }
}

// ---------------------------------------------------------------------------
// Flash attention fwd, bf16 MFMA, base-2 softmax with defer-max (THR=8).
// Per (b,h, 64-row q-tile), 4 waves x 16 q-rows. P via wave-private swizzled
// LDS rows (conflict-free scalar writes). Outputs ctx bf16 + base-2 m,l.
// ---------------------------------------------------------------------------
__launch_bounds__(256)
__global__ void flash_mfma(const short* __restrict__ q, const short* __restrict__ k,
                           const short* __restrict__ vt, short* __restrict__ ctx,
                           float* __restrict__ mbuf, float* __restrict__ lbuf)
{
    __shared__ short k_lds[64][72];
    __shared__ short vt_lds[64][72];
    __shared__ short p_lds[64][72];

    const int tid = threadIdx.x;
    const int l = tid & 63, w = tid >> 6;
    const int lr = l & 15, lg = l >> 4;
    const int s0 = blockIdx.x * 64;
    const int bh = blockIdx.y;

    const short* qb  = q  + (size_t)bh * S_ * D_;
    const short* kb  = k  + (size_t)bh * S_ * D_;
    const short* vtb = vt + (size_t)bh * D_ * S_;

    bf16x8 qa[2];
#pragma unroll
    for (int c = 0; c < 2; ++c)
        qa[c] = *(const bf16x8*)&qb[(size_t)(s0 + w * 16 + lr) * D_ + c * 32 + lg * 8];

    float m_run[4], l_run[4];
    f32x4 cacc[4];
#pragma unroll
    for (int r = 0; r < 4; ++r) { m_run[r] = -1e30f; l_run[r] = 0.f; }
#pragma unroll
    for (int dt = 0; dt < 4; ++dt) { cacc[dt][0] = 0.f; cacc[dt][1] = 0.f; cacc[dt][2] = 0.f; cacc[dt][3] = 0.f; }

    for (int t0 = 0; t0 < S_; t0 += 64) {
        __syncthreads();
#pragma unroll
        for (int i = 0; i < 2; ++i) {
            int idx = tid + i * 256;            // 512 8-bf16 slots
            int row = idx >> 3, c8 = (idx & 7) * 8;
            *(bf16x8*)&k_lds[row][c8]  = *(const bf16x8*)&kb[(size_t)(t0 + row) * D_ + c8];
            *(bf16x8*)&vt_lds[row][c8] = *(const bf16x8*)&vtb[(size_t)row * S_ + t0 + c8];
        }
        __syncthreads();

        f32x4 sc[4];
#pragma unroll
        for (int nt = 0; nt < 4; ++nt) {
            sc[nt][0] = 0.f; sc[nt][1] = 0.f; sc[nt][2] = 0.f; sc[nt][3] = 0.f;
            bf16x8 k0f = *(const bf16x8*)&k_lds[nt * 16 + lr][lg * 8];
            bf16x8 k1f = *(const bf16x8*)&k_lds[nt * 16 + lr][32 + lg * 8];
            sc[nt] = MFMA(qa[0], k0f, sc[nt]);
            sc[nt] = MFMA(qa[1], k1f, sc[nt]);
        }

        // per-row max (rows = lg*4+r within this wave's 16 rows)
        float mt4[4];
#pragma unroll
        for (int r = 0; r < 4; ++r) {
            float m_ = fmaxf(fmaxf(sc[0][r], sc[1][r]), fmaxf(sc[2][r], sc[3][r]));
#pragma unroll
            for (int off = 1; off < 16; off <<= 1)
                m_ = fmaxf(m_, __shfl_xor(m_, off, 16));
            mt4[r] = m_;
        }

        // defer-max: only rescale when some row grew by more than 2^8
        const float need = fmaxf(fmaxf(mt4[0] - m_run[0], mt4[1] - m_run[1]),
                                 fmaxf(mt4[2] - m_run[2], mt4[3] - m_run[3]));
        if (!__all(need <= 8.0f)) {
#pragma unroll
            for (int r = 0; r < 4; ++r) {
                const float mn = fmaxf(m_run[r], mt4[r]);
                const float al = EXP2(m_run[r] - mn);
                m_run[r] = mn;
                l_run[r] *= al;
#pragma unroll
                for (int dt = 0; dt < 4; ++dt) cacc[dt][r] *= al;
            }
        }

        // P = 2^(s - m), write to swizzled wave-private LDS rows
#pragma unroll
        for (int r = 0; r < 4; ++r) {
            const int prow = w * 16 + lg * 4 + r;
            float sig = 0.f;
#pragma unroll
            for (int nt = 0; nt < 4; ++nt) {
                float p = EXP2(sc[nt][r] - m_run[r]);
                sig += p;
                p_lds[prow][(nt * 16 + lr) ^ (lg << 4)] = f2bf(p);
            }
#pragma unroll
            for (int off = 1; off < 16; off <<= 1)
                sig += __shfl_xor(sig, off, 16);
            l_run[r] += sig;
        }

        // PV: ctx += P @ V  (wave-private rows; LDS is in-order per wave)
        const int xr = (lr >> 2) << 4;
        bf16x8 pa[2];
#pragma unroll
        for (int c = 0; c < 2; ++c)
            pa[c] = *(const bf16x8*)&p_lds[w * 16 + lr][(c * 32 + lg * 8) ^ xr];
#pragma unroll
        for (int dt = 0; dt < 4; ++dt) {
            bf16x8 v0f = *(const bf16x8*)&vt_lds[dt * 16 + lr][lg * 8];
            bf16x8 v1f = *(const bf16x8*)&vt_lds[dt * 16 + lr][32 + lg * 8];
            cacc[dt] = MFMA(pa[0], v0f, cacc[dt]);
            cacc[dt] = MFMA(pa[1], v1f, cacc[dt]);
        }
    }

    const int b = bh >> 4, h = bh & 15;
#pragma unroll
    for (int r = 0; r < 4; ++r) {
        const float linv = RCP(l_run[r]);
        const int srow = s0 + w * 16 + lg * 4 + r;
#pragma unroll
        for (int dt = 0; dt < 4; ++dt)
            ctx[((size_t)(b * S_ + srow)) * E_ + h * D_ + dt * 16 + lr] = f2bf(cacc[dt][r] * linv);
        if (lr == 0) {
            mbuf[(size_t)bh * S_ + srow] = m_run[r];
            lbuf[(size_t)bh * S_ + srow] = l_run[r];
        }
    }
}

// ---------------------------------------------------------------------------
// attn_avg, bf16 MFMA: per (b, 128 s-rows, 128 t-cols), loop 16 heads,
// recompute scores (identical MFMA inputs to flash) with saved base-2 m,l.
// ---------------------------------------------------------------------------
__launch_bounds__(256)
__global__ void avg_mfma(const short* __restrict__ q, const short* __restrict__ k,
                         const float* __restrict__ mbuf, const float* __restrict__ lbuf,
                         float* __restrict__ avg)
{
    __shared__ short qs[128][72];
    __shared__ short ks[128][72];

    const int tid = threadIdx.x;
    const int l = tid & 63, w = tid >> 6;
    const int lr = l & 15, lg = l >> 4;
    const int b = blockIdx.z;
    const int s0 = blockIdx.y * 128;
    const int t0 = blockIdx.x * 128;

    f32x4 acc[2][8];
#pragma unroll
    for (int mt = 0; mt < 2; ++mt)
#pragma unroll
        for (int nt = 0; nt < 8; ++nt) { acc[mt][nt][0] = 0.f; acc[mt][nt][1] = 0.f; acc[mt][nt][2] = 0.f; acc[mt][nt][3] = 0.f; }

    for (int h = 0; h < H_; ++h) {
        const int bh = b * H_ + h;
        const short* qb = q + (size_t)bh * S_ * D_;
        const short* kb = k + (size_t)bh * S_ * D_;
        __syncthreads();
#pragma unroll
        for (int i = 0; i < 4; ++i) {
            int idx = tid + i * 256;            // 1024 8-bf16 slots
            int row = idx >> 3, c8 = (idx & 7) * 8;
            *(bf16x8*)&qs[row][c8] = *(const bf16x8*)&qb[(size_t)(s0 + row) * D_ + c8];
            *(bf16x8*)&ks[row][c8] = *(const bf16x8*)&kb[(size_t)(t0 + row) * D_ + c8];
        }
        __syncthreads();

#pragma unroll
        for (int mt = 0; mt < 2; ++mt) {
            bf16x8 qa0 = *(const bf16x8*)&qs[w * 32 + mt * 16 + lr][lg * 8];
            bf16x8 qa1 = *(const bf16x8*)&qs[w * 32 + mt * 16 + lr][32 + lg * 8];
            float mv[4], li[4];
#pragma unroll
            for (int r = 0; r < 4; ++r) {
                const int srow = s0 + w * 32 + mt * 16 + lg * 4 + r;
                mv[r] = mbuf[(size_t)bh * S_ + srow];
                li[r] = RCP(lbuf[(size_t)bh * S_ + srow]);
            }
#pragma unroll
            for (int nt = 0; nt < 8; ++nt) {
                bf16x8 kb0 = *(const bf16x8*)&ks[nt * 16 + lr][lg * 8];
                bf16x8 kb1 = *(const bf16x8*)&ks[nt * 16 + lr][32 + lg * 8];
                f32x4 sv; sv[0] = 0.f; sv[1] = 0.f; sv[2] = 0.f; sv[3] = 0.f;
                sv = MFMA(qa0, kb0, sv);
                sv = MFMA(qa1, kb1, sv);
#pragma unroll
                for (int r = 0; r < 4; ++r)
                    acc[mt][nt][r] += EXP2(sv[r] - mv[r]) * li[r];
            }
        }
    }

#pragma unroll
    for (int mt = 0; mt < 2; ++mt)
#pragma unroll
        for (int nt = 0; nt < 8; ++nt)
#pragma unroll
            for (int r = 0; r < 4; ++r) {
                const int srow = s0 + w * 32 + mt * 16 + lg * 4 + r;
                avg[((size_t)(b * S_ + srow)) * S_ + t0 + nt * 16 + lr] = acc[mt][nt][r] * 0.0625f;
            }
}

// ---------------------------------------------------------------------------
extern "C" void kernel_launch(void* const* d_in, const int* in_sizes, int n_in,
                              void* d_out, int out_size, void* d_ws, size_t ws_size,
                              hipStream_t stream)
{
    const float* x  = (const float*)d_in[0];
    const float* Wq = (const float*)d_in[1];
    const float* bq = (const float*)d_in[2];
    const float* Wk = (const float*)d_in[3];
    const float* bk = (const float*)d_in[4];
    const float* Wv = (const float*)d_in[5];
    const float* bv = (const float*)d_in[6];
    const float* Wo = (const float*)d_in[7];
    const float* bo = (const float*)d_in[8];

    float* out = (float*)d_out;                        // [B,S,E] fp32
    float* avg = out + (size_t)B_ * S_ * E_;           // [B,S,S] fp32

    const size_t NX = (size_t)B_ * S_ * E_;            // 8.39M
    const size_t NW = (size_t)E_ * E_;                 // 1.05M
    const size_t NQ = (size_t)B_ * H_ * S_ * D_;       // 8.39M

    short* xb   = (short*)d_ws;    // bf16 x; DEAD after QKV GEMM
    short* wqb  = xb  + NX;
    short* wkb  = wqb + NW;
    short* wvb  = wkb + NW;
    short* wob  = wvb + NW;
    short* qw   = wob + NW;        // bf16 [B,H,S,D], pre-scaled by QSCALE
    short* kw   = qw  + NQ;        // bf16 [B,H,S,D]
    short* vtw  = kw  + NQ;        // bf16 [B,H,D,S]
    float* mb   = (float*)(vtw + NQ);
    float* lb   = mb + (size_t)B_ * H_ * S_;           // ~76 MB total
    short* ctxw = xb;              // bf16 [B,S,E]; aliases xb (dead by then)

    cvt_bf16_5<<<dim3(512, 5), 256, 0, stream>>>(x, Wq, Wk, Wv, Wo,
                                                 xb, wqb, wkb, wvb, wob);

    gemm_mfma<0><<<dim3(E_ / 128, (B_ * S_) / 128, 3), 256, 0, stream>>>(
        xb, wqb, bq, qw, wkb, bk, kw, wvb, bv, vtw, nullptr);

    flash_mfma<<<dim3(S_ / 64, B_ * H_), 256, 0, stream>>>(qw, kw, vtw, ctxw, mb, lb);

    gemm_mfma<1><<<dim3(E_ / 128, (B_ * S_) / 128, 1), 256, 0, stream>>>(
        ctxw, wob, bo, nullptr, nullptr, nullptr, nullptr,
        nullptr, nullptr, nullptr, out);

    avg_mfma<<<dim3(S_ / 128, S_ / 128, B_), 256, 0, stream>>>(qw, kw, mb, lb, avg);
}